// Round 1
// baseline (173.161 us; speedup 1.0000x reference)
//
#include <hip/hip_runtime.h>

#define THREADS 256

// out[i][v] = fc_bias[v] + sum_k u_k(theta_i) * A[k][v]
//   u_k = C^(4-k) * S^k,  C = cos^2(theta/2) = 0.5 + 0.5*cos(theta),  S = 1 - C
//   A[k][v] = sum_q Z[k][q] * fc_weight[v][q]
// Z[k][q] = sum of z-signs over basis states b with popcount(P(b)) == k,
// P = composition of the 3 CNOT perms (compile-time constant).
// q_weights drops out: |exp(-0.5j*real)| == 1, so probs = state^2.
__global__ __launch_bounds__(THREADS) void sqm_kernel(
    const float* __restrict__ x,     // [n]
    const float* __restrict__ fcw,   // [40][4]
    const float* __restrict__ fcb,   // [40]
    float* __restrict__ out,         // [n][40]
    int n)
{
    const int Z[5][4] = {
        { 1, 1, 1, 1},
        { 2, 0,-2,-4},
        { 0,-2, 0, 6},
        {-2, 0, 2,-4},
        {-1, 1,-1, 1},
    };

    __shared__ __align__(16) float sA[5][40];
    __shared__ __align__(16) float sB[40];
    __shared__ float sU[THREADS * 5];   // stride 5 (coprime to 32 banks)

    const int t = threadIdx.x;

    // Phase 0: build A and bias in LDS (fc_weight is tiny, L2-resident)
    if (t < 200) {
        const int k = t / 40, v = t % 40;
        float a = 0.f;
        #pragma unroll
        for (int q = 0; q < 4; ++q) a += (float)Z[k][q] * fcw[v * 4 + q];
        sA[k][v] = a;
    } else if (t < 240) {
        sB[t - 200] = fcb[t - 200];
    }

    // Phase 1: per-row power basis u[5]
    const long long base = (long long)blockIdx.x * THREADS;
    const int i = (int)(base + t);
    const float theta = (i < n) ? x[i] : 0.f;
    const float C = 0.5f + 0.5f * __cosf(theta);
    const float S = 1.f - C;
    const float C2 = C * C, S2 = S * S, CS = C * S;
    sU[t * 5 + 0] = C2 * C2;
    sU[t * 5 + 1] = C2 * CS;
    sU[t * 5 + 2] = CS * CS;
    sU[t * 5 + 3] = CS * S2;
    sU[t * 5 + 4] = S2 * S2;
    __syncthreads();

    // Phase 2: cooperative coalesced write. Block owns 256 rows * 40 floats
    // = 2560 float4s, flat-indexed so consecutive lanes store consecutive 16B.
    float4* __restrict__ out4 = reinterpret_cast<float4*>(out);
    const long long blockF4 = (long long)blockIdx.x * (THREADS * 10);
    const long long totalF4 = (long long)n * 10;
    #pragma unroll
    for (int kk = 0; kk < 10; ++kk) {
        const int j = t + kk * THREADS;          // 0..2559 within block
        const long long gj = blockF4 + j;
        if (gj < totalF4) {
            const int row = j / 10;
            const int c4  = (j - row * 10) * 4;  // output column start (0,4,..,36)
            const float u0 = sU[row * 5 + 0];
            const float u1 = sU[row * 5 + 1];
            const float u2 = sU[row * 5 + 2];
            const float u3 = sU[row * 5 + 3];
            const float u4 = sU[row * 5 + 4];
            const float4 a0 = *reinterpret_cast<const float4*>(&sA[0][c4]);
            const float4 a1 = *reinterpret_cast<const float4*>(&sA[1][c4]);
            const float4 a2 = *reinterpret_cast<const float4*>(&sA[2][c4]);
            const float4 a3 = *reinterpret_cast<const float4*>(&sA[3][c4]);
            const float4 a4 = *reinterpret_cast<const float4*>(&sA[4][c4]);
            const float4 b  = *reinterpret_cast<const float4*>(&sB[c4]);
            float4 r;
            r.x = b.x + u0*a0.x + u1*a1.x + u2*a2.x + u3*a3.x + u4*a4.x;
            r.y = b.y + u0*a0.y + u1*a1.y + u2*a2.y + u3*a3.y + u4*a4.y;
            r.z = b.z + u0*a0.z + u1*a1.z + u2*a2.z + u3*a3.z + u4*a4.z;
            r.w = b.w + u0*a0.w + u1*a1.w + u2*a2.w + u3*a3.w + u4*a4.w;
            out4[gj] = r;
        }
    }
}

extern "C" void kernel_launch(void* const* d_in, const int* in_sizes, int n_in,
                              void* d_out, int out_size, void* d_ws, size_t ws_size,
                              hipStream_t stream) {
    const float* x   = (const float*)d_in[0];
    // d_in[1] = q_weights: unused — unit-magnitude phase cancels in |psi|^2
    const float* fcw = (const float*)d_in[2];
    const float* fcb = (const float*)d_in[3];
    float* out = (float*)d_out;
    const int n = in_sizes[0];
    const int grid = (n + THREADS - 1) / THREADS;
    hipLaunchKernelGGL(sqm_kernel, dim3(grid), dim3(THREADS), 0, stream,
                       x, fcw, fcb, out, n);
}